// Round 6
// baseline (567.401 us; speedup 1.0000x reference)
//
#include <hip/hip_runtime.h>
#include <hip/hip_bf16.h>
#include <stdint.h>

// ---------------------------------------------------------------------------
// InterFusion, fp32 I/O: LN1 -> QKV(fused N=3072) -> attn(S=2) ->
// O-proj(+resid -> out1 bf16 in ws) -> LN2 -> FFN1 -> FFN2(+resid -> fp32 out).
// GEMM: 256x256 tile, 8 waves (2Mx4N), double-buffered 64-K slots.
// r5 lesson: barrier-minimal TILE with 6 live frag arrays (96 VGPR) spilled
// (WRITE_SIZE +15MB = scratch). This round keeps the 1-barrier-per-tile
// structure but bounds fragment liveness to <=16 short8 (64 VGPR) with a
// ping-pong read order: each MFMA cluster has the NEXT cluster's ds_reads
// issued ahead of it (LDS pipe || MFMA pipe), staging interleaved, single
// vmcnt(0)+s_barrier at tile end. Compiler inserts counted lgkmcnt.
// ---------------------------------------------------------------------------

typedef __attribute__((ext_vector_type(8))) short short8;   // 8 bf16 = 4 VGPR
typedef __attribute__((ext_vector_type(4))) float floatx4;  // MFMA acc

__device__ __forceinline__ float b2f(short s) {
  union { unsigned u; float f; } v;
  v.u = ((unsigned)(unsigned short)s) << 16;
  return v.f;
}
__device__ __forceinline__ short f2b(float f) {
  union { float f; unsigned u; } v;
  v.f = f;
  unsigned r = v.u + 0x7FFFu + ((v.u >> 16) & 1u);  // RNE
  return (short)(r >> 16);
}
__device__ __forceinline__ float fast_tanh(float x) {
  float e = __expf(2.f * x);
  return 1.f - 2.f / (e + 1.f);
}
__device__ __forceinline__ void load16_lds(const void* g, void* l) {
  __builtin_amdgcn_global_load_lds(
      (__attribute__((address_space(1))) void*)(void*)g,
      (__attribute__((address_space(3))) void*)l, 16, 0, 0);
}

// ---------------------------------------------------------------------------
// 4-source fp32 -> bf16 conversion into one contiguous bf16 region.
// ---------------------------------------------------------------------------
struct Src4 { const float* p[4]; };

__global__ __launch_bounds__(256) void cvt4_kernel(Src4 s,
                                                   short* __restrict__ y,
                                                   int sh) {
  const int i = blockIdx.x * 256 + threadIdx.x;  // global 8-elem index
  const int seg = i >> sh;
  const int off = i & ((1 << sh) - 1);
  const float* x = s.p[seg];
  const float4 a = ((const float4*)x)[(size_t)off * 2];
  const float4 b = ((const float4*)x)[(size_t)off * 2 + 1];
  short8 r;
  r[0] = f2b(a.x); r[1] = f2b(a.y); r[2] = f2b(a.z); r[3] = f2b(a.w);
  r[4] = f2b(b.x); r[5] = f2b(b.y); r[6] = f2b(b.z); r[7] = f2b(b.w);
  ((short8*)y)[i] = r;
}

// ---------------------------------------------------------------------------
// GEMM: C[M,N] = A[M,K] @ W[N,K]^T (bf16 in, fp32 acc), 256x256 tile.
// grid = (N/256, M/256, ZSEL?2:1), block = 512 (8 waves, 2Mx4N of 128x64).
// LDS (dynamic 128 KiB): A slot0|A slot1|B slot0|B slot1, each 256x64 bf16,
// granule-swizzled: row r, granule-slot g holds global granule g^(r&7).
// Per 64-K tile: ping-pong frag reads ahead of MFMA clusters (liveness
// <=16 short8), 8 stage issues interleaved, vmcnt(0)+s_barrier at end
// (skipped on last tile).
// EPI 0: store bf16
// EPI 1: c + aux_f32[r][n], store bf16            (out1 = Oproj + input)
// EPI 2: tanh(c + bias[n]), store bf16            (FFN hidden)
// EPI 3: tanh(c + bias[n]) + b2f(res_bf16), store fp32   (final output)
// ZSEL: blockIdx.z==1 -> Wz/biasz, A += a_zoff, C/res += c_zoff.
// ---------------------------------------------------------------------------
template <int EPI, int ZSEL>
__global__ __launch_bounds__(512, 2) void gemm256(
    const short* A, int lda, const short* W, int K, void* Cout, int ldc,
    const float* aux, int ld_aux, const float* bias, const short* res, int ldr,
    const short* Wz, const float* biasz, int a_zoff, int c_zoff) {
  extern __shared__ short lds[];  // 65536 shorts = 128 KiB
  const int tid = threadIdx.x;
  const int lane = tid & 63;
  const int wid = tid >> 6;
  const int l15 = lane & 15;
  const int l4 = lane >> 4;
  const int wm = (wid >> 2) * 128;  // wave M offset in tile
  const int wn = (wid & 3) * 64;    // wave N offset in tile

  // bijective XCD-aware block swizzle (nwg % 8 == 0 for all our launches)
  const int gx = gridDim.x;
  const int nwg = gx * gridDim.y;
  const int bid0 = blockIdx.y * gx + blockIdx.x;
  const int bid = (bid0 & 7) * (nwg >> 3) + (bid0 >> 3);
  const int bn0 = (bid % gx) * 256;
  const int bm0 = (bid / gx) * 256;

  const short* Wp = W;
  const float* bp = bias;
  int coff = 0;
  if (ZSEL && blockIdx.z) {
    Wp = Wz;
    bp = biasz;
    A += a_zoff;
    coff = c_zoff;
  }

  floatx4 zero = {0.f, 0.f, 0.f, 0.f};
  floatx4 acc[8][4];
#pragma unroll
  for (int i = 0; i < 8; ++i)
#pragma unroll
    for (int j = 0; j < 4; ++j) acc[i][j] = zero;

  // staging: issue e covers rows e*8..e*8+7 (e = wid*4 + t, t=0..3 -> 256
  // rows across 8 waves); lane loads granule (lane&7)^r8 of row e*8+r8 ->
  // lands at LDS granule-slot (lane&7) of its row.
  const int r8 = lane >> 3;
  const int gsw = (lane & 7) ^ r8;
  const int aoff = r8 * lda + gsw * 8;  // per-lane element offset (VGPR)
  const int boff = r8 * K + gsw * 8;
  const short* Ab = A + (size_t)bm0 * lda;  // wave-uniform
  const short* Bb = Wp + (size_t)bn0 * K;   // wave-uniform
  const int e0 = __builtin_amdgcn_readfirstlane(wid * 4);
  const int swz = l15 & 7;  // read-side swizzle key (= fragment row & 7)

  short* As0 = lds;            // A slot0: 256x64
  short* As1 = lds + 16384;    // A slot1
  short* Bs0 = lds + 32768;    // B slot0
  short* Bs1 = lds + 49152;    // B slot1

#define STAGE_A(slotptr, t, tk0) \
  load16_lds(Ab + (size_t)(e0 + (t)) * 8 * lda + (tk0) + aoff, \
             (slotptr) + (e0 + (t)) * 512)
#define STAGE_B(slotptr, t, tk0) \
  load16_lds(Bb + (size_t)(e0 + (t)) * 8 * K + (tk0) + boff, \
             (slotptr) + (e0 + (t)) * 512)

#define MFMA16(AV, BV, AI)                                                   \
  __builtin_amdgcn_s_setprio(1);                                             \
  _Pragma("unroll") for (int i = 0; i < 4; ++i)                              \
      _Pragma("unroll") for (int j = 0; j < 4; ++j)                          \
          acc[(AI) + i][j] = __builtin_amdgcn_mfma_f32_16x16x32_bf16(        \
              (AV)[i], (BV)[j], acc[(AI) + i][j], 0, 0, 0);                  \
  __builtin_amdgcn_s_setprio(0);

  // One 64-K tile: ping-pong fragment reads ahead of MFMA clusters.
  // Liveness bound: at most {consumed set + loading set} = 16 short8.
#define TILE(Asl, Bsl, Anx, Bnx, knext, domore)                              \
  {                                                                          \
    const int ko0 = (l4 ^ swz) * 8;                                          \
    const int ko1 = ((4 + l4) ^ swz) * 8;                                    \
    short8 bv0[4], aA[4];                                                    \
    _Pragma("unroll") for (int j = 0; j < 4; ++j)                            \
        bv0[j] = *(const short8*)&(Bsl)[(wn + j * 16 + l15) * 64 + ko0];     \
    _Pragma("unroll") for (int i = 0; i < 4; ++i)                            \
        aA[i] = *(const short8*)&(Asl)[(wm + i * 16 + l15) * 64 + ko0];      \
    short8 aB[4];                                                            \
    _Pragma("unroll") for (int i = 0; i < 4; ++i)                            \
        aB[i] = *(const short8*)&(Asl)[(wm + 64 + i * 16 + l15) * 64 + ko0]; \
    if (domore) {                                                            \
      STAGE_A(Anx, 0, knext); STAGE_B(Bnx, 0, knext);                        \
      STAGE_A(Anx, 1, knext); STAGE_B(Bnx, 1, knext);                        \
    }                                                                        \
    MFMA16(aA, bv0, 0)                                                       \
    short8 bv1[4], aA1[4];                                                   \
    _Pragma("unroll") for (int j = 0; j < 4; ++j)                            \
        bv1[j] = *(const short8*)&(Bsl)[(wn + j * 16 + l15) * 64 + ko1];     \
    _Pragma("unroll") for (int i = 0; i < 4; ++i)                            \
        aA1[i] = *(const short8*)&(Asl)[(wm + i * 16 + l15) * 64 + ko1];     \
    if (domore) {                                                            \
      STAGE_A(Anx, 2, knext); STAGE_B(Bnx, 2, knext);                        \
      STAGE_A(Anx, 3, knext); STAGE_B(Bnx, 3, knext);                        \
    }                                                                        \
    MFMA16(aB, bv0, 4)                                                       \
    short8 aB1[4];                                                           \
    _Pragma("unroll") for (int i = 0; i < 4; ++i)                            \
        aB1[i] = *(const short8*)&(Asl)[(wm + 64 + i * 16 + l15) * 64 + ko1];\
    MFMA16(aA1, bv1, 0)                                                      \
    MFMA16(aB1, bv1, 4)                                                      \
    if (domore) {                                                            \
      asm volatile("s_waitcnt vmcnt(0)" ::: "memory");                       \
      __builtin_amdgcn_s_barrier();                                          \
      asm volatile("" ::: "memory");                                         \
    }                                                                        \
  }

  // prologue: stage tile0 -> slot0, drain, publish
#pragma unroll
  for (int t = 0; t < 4; ++t) {
    STAGE_A(As0, t, 0);
    STAGE_B(Bs0, t, 0);
  }
  asm volatile("s_waitcnt vmcnt(0)" ::: "memory");
  __builtin_amdgcn_s_barrier();
  asm volatile("" ::: "memory");

  const int nit = K >> 7;  // K/128 (two 64-wide tiles per iteration)
  for (int it = 0; it < nit; ++it) {
    const int kodd = it * 128 + 64;
    const int knext = it * 128 + 128;
    const bool more = (it + 1 < nit);
    TILE(As0, Bs0, As1, Bs1, kodd, true)   // compute even slot, stage odd
    TILE(As1, Bs1, As0, Bs0, knext, more)  // compute odd slot, stage next
  }
#undef TILE
#undef MFMA16
#undef STAGE_A
#undef STAGE_B

  // epilogue: lane holds C[mb + i*16 + p][nb + j*16], p = 0..3, i = 0..7
  const int mb = bm0 + wm + l4 * 4;
  const int nb = bn0 + wn + l15;
#pragma unroll
  for (int i = 0; i < 8; ++i) {
#pragma unroll
    for (int p = 0; p < 4; ++p) {
      const int r = mb + i * 16 + p;
#pragma unroll
      for (int j = 0; j < 4; ++j) {
        const int n = nb + j * 16;
        float c = acc[i][j][p];
        if (EPI == 0) {
          ((short*)Cout)[(size_t)r * ldc + n + coff] = f2b(c);
        } else if (EPI == 1) {
          ((short*)Cout)[(size_t)r * ldc + n + coff] =
              f2b(c + aux[(size_t)r * ld_aux + n]);
        } else if (EPI == 2) {
          ((short*)Cout)[(size_t)r * ldc + n + coff] =
              f2b(fast_tanh(c + bp[n]));
        } else {
          const float rv = b2f(res[(size_t)r * ldr + n + coff]);
          ((float*)Cout)[(size_t)r * ldc + n + coff] =
              fast_tanh(c + bp[n]) + rv;
        }
      }
    }
  }
}

// ---------------------------------------------------------------------------
// LayerNorm over (S,E) = 2048 elems per batch. One block per batch.
// ---------------------------------------------------------------------------
template <int INBF16>
__global__ __launch_bounds__(256) void ln_kernel(const void* __restrict__ xin,
                                                 const float* __restrict__ w,
                                                 const float* __restrict__ bb,
                                                 short* __restrict__ y) {
  const int b = blockIdx.x;
  const int tid = threadIdx.x;
  const size_t base = (size_t)b * 2048 + tid * 8;
  float xv[8];
  if (INBF16) {
    short8 s = *(const short8*)((const short*)xin + base);
#pragma unroll
    for (int j = 0; j < 8; ++j) xv[j] = b2f(s[j]);
  } else {
    const float4 a = *(const float4*)((const float*)xin + base);
    const float4 c = *(const float4*)((const float*)xin + base + 4);
    xv[0] = a.x; xv[1] = a.y; xv[2] = a.z; xv[3] = a.w;
    xv[4] = c.x; xv[5] = c.y; xv[6] = c.z; xv[7] = c.w;
  }
  float sum = 0.f, sq = 0.f;
#pragma unroll
  for (int j = 0; j < 8; ++j) {
    sum += xv[j];
    sq += xv[j] * xv[j];
  }
  __shared__ float rs[8];
  const int lane = tid & 63, wid = tid >> 6;
#pragma unroll
  for (int off = 32; off; off >>= 1) {
    sum += __shfl_down(sum, off);
    sq += __shfl_down(sq, off);
  }
  if (lane == 0) {
    rs[wid] = sum;
    rs[4 + wid] = sq;
  }
  __syncthreads();
  const float stot = rs[0] + rs[1] + rs[2] + rs[3];
  const float qtot = rs[4] + rs[5] + rs[6] + rs[7];
  const float mean = stot * (1.f / 2048.f);
  const float rstd = rsqrtf(qtot * (1.f / 2048.f) - mean * mean + 1e-5f);
  const int wi = tid * 8;
  short8 r;
#pragma unroll
  for (int j = 0; j < 8; ++j)
    r[j] = f2b((xv[j] - mean) * rstd * w[wi + j] + bb[wi + j]);
  *(short8*)(y + base) = r;
}

// ---------------------------------------------------------------------------
// Attention, S=2, on the fused QKV buffer (row stride 3072: q|k|v columns).
// ---------------------------------------------------------------------------
__global__ __launch_bounds__(256) void attn_kernel(short* qkv) {
  __shared__ short sm[2][6][1032];    // q0,q1,k0,k1,v0,v1
  __shared__ float sps[2][2][2][16];  // [half][s][t][h] scores
  __shared__ float spp[2][2][2][16];  // [half][s][t][h] probs
  const int tid = threadIdx.x;
  const int half = tid >> 7;
  const int t = tid & 127;
  const int b = blockIdx.x * 2 + half;
  const short* row0 = qkv + ((size_t)b * 2 + 0) * 3072;
  const short* row1 = qkv + ((size_t)b * 2 + 1) * 3072;
  const short* srcs[6] = {row0,        row1,        row0 + 1024,
                          row1 + 1024, row0 + 2048, row1 + 2048};
#pragma unroll
  for (int rr = 0; rr < 6; ++rr)
    *(short8*)&sm[half][rr][t * 8] = *(const short8*)(srcs[rr] + t * 8);
  __syncthreads();
  if (t < 64) {
    const int h = t & 15, comb = t >> 4;
    const int si = comb >> 1, ti = comb & 1;
    const short* qr = sm[half][si];
    const short* kr = sm[half][2 + ti];
    float a = 0.f;
#pragma unroll
    for (int d = 0; d < 64; ++d) a += b2f(qr[d * 16 + h]) * b2f(kr[d * 16 + h]);
    sps[half][si][ti][h] = a * 0.125f;  // / sqrt(NH=64)
  }
  __syncthreads();
  if (t < 32) {
    const int h = t & 15, si = t >> 4;
    const float s0 = sps[half][si][0][h], s1 = sps[half][si][1][h];
    const float m = fmaxf(s0, s1);
    const float e0 = __expf(s0 - m), e1 = __expf(s1 - m);
    const float inv = 1.f / (e0 + e1);
    spp[half][si][0][h] = e0 * inv;
    spp[half][si][1][h] = e1 * inv;
  }
  __syncthreads();
#pragma unroll
  for (int si = 0; si < 2; ++si) {
    short8 r;
#pragma unroll
    for (int j = 0; j < 8; ++j) {
      const int e = t * 8 + j;
      const int h = e & 15;
      const float c = spp[half][si][0][h] * b2f(sm[half][4][e]) +
                      spp[half][si][1][h] * b2f(sm[half][5][e]);
      r[j] = f2b(c);
    }
    *(short8*)(qkv + ((size_t)b * 2 + si) * 3072 + t * 8) = r;
  }
}

// ---------------------------------------------------------------------------
extern "C" void kernel_launch(void* const* d_in, const int* in_sizes, int n_in,
                              void* d_out, int out_size, void* d_ws,
                              size_t ws_size, hipStream_t stream) {
  (void)in_sizes; (void)n_in; (void)out_size; (void)ws_size;
  const float* input = (const float*)d_in[0];
  const float* Wq = (const float*)d_in[1];
  const float* Wk = (const float*)d_in[2];
  const float* Wv = (const float*)d_in[3];
  const float* Wo = (const float*)d_in[4];
  const float* ln1w = (const float*)d_in[5];
  const float* ln1b = (const float*)d_in[6];
  const float* ln2w = (const float*)d_in[7];
  const float* ln2b = (const float*)d_in[8];
  const float* f1w1 = (const float*)d_in[9];
  const float* f1b1 = (const float*)d_in[10];
  const float* f1w2 = (const float*)d_in[11];
  const float* f1b2 = (const float*)d_in[12];
  const float* f2w1 = (const float*)d_in[13];
  const float* f2b1 = (const float*)d_in[14];
  const float* f2w2 = (const float*)d_in[15];
  const float* f2b2 = (const float*)d_in[16];
  float* out = (float*)d_out;
  char* ws = (char*)d_ws;

  const size_t MB = 1024 * 1024;
  dim3 blk(256);
  dim3 gblk(512);
  const int GLDS = 131072;  // 128 KiB dynamic LDS for gemm256

  // allow 128 KiB dynamic LDS (idempotent, host-side, capture-safe)
  {
    auto set = [](const void* f) {
      (void)hipFuncSetAttribute(f, hipFuncAttributeMaxDynamicSharedMemorySize,
                                131072);
    };
    set((const void*)gemm256<0, 0>);
    set((const void*)gemm256<1, 0>);
    set((const void*)gemm256<2, 1>);
    set((const void*)gemm256<3, 1>);
  }

  // ws layout:
  //   phase 1: wqkv+wo [0,8) | xs->out1 [8,40) | qkv [40,136)   (136 MiB)
  //   phase 2: out1 [8,40) | fw [40,56) | hb [56,120)            (120 MiB)
  //   outs (LN2 output, 8192x2048 bf16 = 32 MiB) lives in d_out.
  short* wqkv = (short*)ws;
  short* wo = (short*)(ws + 6 * MB);
  short* xs = (short*)(ws + 8 * MB);
  short* out1 = xs;  // overwrites xs (dead after QKV GEMM)
  short* qkvb = (short*)(ws + 40 * MB);

  // ---- Phase 1 -----------------------------------------------------------
  {
    Src4 s{{Wq, Wk, Wv, Wo}};
    cvt4_kernel<<<2048, blk, 0, stream>>>(s, wqkv, 17);  // 4 x 1M elems
  }
  ln_kernel<0><<<8192, blk, 0, stream>>>(input, ln1w, ln1b, xs);
  {
    dim3 g(12, 64);  // 768 blocks, 1/CU -> 3 residency waves
    gemm256<0, 0><<<g, gblk, GLDS, stream>>>(xs, 1024, wqkv, 1024, qkvb, 3072,
                                             nullptr, 0, nullptr, nullptr, 0,
                                             nullptr, nullptr, 0, 0);
  }
  attn_kernel<<<4096, blk, 0, stream>>>(qkvb);
  {
    dim3 g(4, 64);  // 256 blocks = 1 residency wave
    // out1 = concat @ Wo^T + input  -> bf16 (overwrites xs)
    gemm256<1, 0><<<g, gblk, GLDS, stream>>>(qkvb, 3072, wo, 1024, out1, 1024,
                                             input, 1024, nullptr, nullptr, 0,
                                             nullptr, nullptr, 0, 0);
  }

  // ---- Phase 2 (unchunked) ----------------------------------------------
  short* fw1s0 = (short*)(ws + 40 * MB);
  short* fw1s1 = (short*)(ws + 44 * MB);
  short* fw2s0 = (short*)(ws + 48 * MB);
  short* fw2s1 = (short*)(ws + 52 * MB);
  short* hb = (short*)(ws + 56 * MB);  // 8192 x 4096 bf16 (64 MiB)
  short* outs = (short*)out;           // d_out reused as bf16 LN2 output
  {
    Src4 s{{f1w1, f2w1, f1w2, f2w2}};
    cvt4_kernel<<<4096, blk, 0, stream>>>(s, fw1s0, 18);  // 4 x 2M elems
  }
  ln_kernel<1><<<8192, blk, 0, stream>>>(out1, ln2w, ln2b, outs);
  {
    // h_s = tanh(outs_s @ w1_s^T + b1_s): M=8192, N=2048, K=1024, z=s
    dim3 g1(8, 32, 2);  // 512 blocks = 2 residency waves
    gemm256<2, 1><<<g1, gblk, GLDS, stream>>>(
        outs, 2048, fw1s0, 1024, hb, 4096, nullptr, 0, f1b1, nullptr, 0,
        fw1s1, f2b1, /*a_zoff=*/1024, /*c_zoff=*/2048);
    // out_s = tanh(h_s @ w2_s^T + b2_s) + out1_s  (fp32 -> d_out)
    dim3 g2(4, 32, 2);  // 256 blocks = 1 residency wave
    gemm256<3, 1><<<g2, gblk, GLDS, stream>>>(
        hb, 4096, fw2s0, 2048, out, 2048, nullptr, 0, f1b2, out1, 2048,
        fw2s1, f2b2, /*a_zoff=*/2048, /*c_zoff=*/1024);
  }
}

// Round 7
// 545.712 us; speedup vs baseline: 1.0397x; 1.0397x over previous
//
#include <hip/hip_runtime.h>
#include <hip/hip_bf16.h>
#include <stdint.h>

// ---------------------------------------------------------------------------
// InterFusion, fp32 I/O: LN1 -> QKV(fused N=3072) -> attn(S=2) ->
// O-proj(+resid -> out1 bf16 in ws) -> LN2 -> FFN1 -> FFN2(+resid -> fp32 out).
// GEMM: 256x256 tile, 8 waves (2Mx4N), r4's measured 8-phase lockstep
// schedule (2 barriers/phase, front-loaded stages, vmcnt(0) at tile
// boundaries) with ONE change: MFMA shape 16x16x32 -> 32x32x16
// (4061 vs 3378 FLOP/cy/CU, half the instruction count, same bytes).
// Per phase: 4 A-reads + 2 B-reads (b128) + 8x mfma_32x32x16.
// C/D mapping (m74/m101): col=lane&31, row=(reg&3)+8*(reg>>2)+4*(lane>>5).
// r5/r6 lesson: hoisted fragment arrays spill at the 128-VGPR cap -> keep
// the r2/r4 lockstep liveness pattern exactly.
// ---------------------------------------------------------------------------

typedef __attribute__((ext_vector_type(8))) short short8;     // 8 bf16
typedef __attribute__((ext_vector_type(16))) float floatx16;  // 32x32 acc

__device__ __forceinline__ float b2f(short s) {
  union { unsigned u; float f; } v;
  v.u = ((unsigned)(unsigned short)s) << 16;
  return v.f;
}
__device__ __forceinline__ short f2b(float f) {
  union { float f; unsigned u; } v;
  v.f = f;
  unsigned r = v.u + 0x7FFFu + ((v.u >> 16) & 1u);  // RNE
  return (short)(r >> 16);
}
__device__ __forceinline__ float fast_tanh(float x) {
  float e = __expf(2.f * x);
  return 1.f - 2.f / (e + 1.f);
}
__device__ __forceinline__ void load16_lds(const void* g, void* l) {
  __builtin_amdgcn_global_load_lds(
      (__attribute__((address_space(1))) void*)(void*)g,
      (__attribute__((address_space(3))) void*)l, 16, 0, 0);
}

// ---------------------------------------------------------------------------
// 4-source fp32 -> bf16 conversion into one contiguous bf16 region.
// ---------------------------------------------------------------------------
struct Src4 { const float* p[4]; };

__global__ __launch_bounds__(256) void cvt4_kernel(Src4 s,
                                                   short* __restrict__ y,
                                                   int sh) {
  const int i = blockIdx.x * 256 + threadIdx.x;  // global 8-elem index
  const int seg = i >> sh;
  const int off = i & ((1 << sh) - 1);
  const float* x = s.p[seg];
  const float4 a = ((const float4*)x)[(size_t)off * 2];
  const float4 b = ((const float4*)x)[(size_t)off * 2 + 1];
  short8 r;
  r[0] = f2b(a.x); r[1] = f2b(a.y); r[2] = f2b(a.z); r[3] = f2b(a.w);
  r[4] = f2b(b.x); r[5] = f2b(b.y); r[6] = f2b(b.z); r[7] = f2b(b.w);
  ((short8*)y)[i] = r;
}

// ---------------------------------------------------------------------------
// GEMM: C[M,N] = A[M,K] @ W[N,K]^T (bf16 in, fp32 acc), 256x256 tile.
// grid = (N/256, M/256, ZSEL?2:1), block = 512 (8 waves, 2Mx4N of 128x64).
// LDS (dynamic 128 KiB): A slot0|A slot1|B slot0|B slot1, each 256x64 bf16,
// granule-swizzled: row r, granule-slot g holds global granule g^(r&7).
// K-loop iteration = 2 K-tiles (128 elems), 8 phases (one 16-wide k-step
// each). Phase p of a tile: [stages] | 4 A + 2 B frag reads (granule
// 2p+(lane>>5), slot XOR lane&7) | barrier | prio1 8x mfma_32x32x16 prio0
// | [boundary vmcnt(0)] | barrier. Stages front-loaded in phases 0-1.
// EPI 0: store bf16
// EPI 1: c + aux_f32[r][n], store bf16            (out1 = Oproj + input)
// EPI 2: tanh(c + bias[n]), store bf16            (FFN hidden)
// EPI 3: tanh(c + bias[n]) + b2f(res_bf16), store fp32   (final output)
// ZSEL: blockIdx.z==1 -> Wz/biasz, A += a_zoff, C/res += c_zoff.
// ---------------------------------------------------------------------------
template <int EPI, int ZSEL>
__global__ __launch_bounds__(512, 2) void gemm256(
    const short* A, int lda, const short* W, int K, void* Cout, int ldc,
    const float* aux, int ld_aux, const float* bias, const short* res, int ldr,
    const short* Wz, const float* biasz, int a_zoff, int c_zoff) {
  extern __shared__ short lds[];  // 65536 shorts = 128 KiB
  const int tid = threadIdx.x;
  const int lane = tid & 63;
  const int wid = tid >> 6;
  const int l31 = lane & 31;
  const int lh = lane >> 5;   // 0/1: granule half
  const int swz7 = lane & 7;  // read-side swizzle key (= row & 7)
  const int wm = (wid >> 2) * 128;  // wave M offset in tile
  const int wn = (wid & 3) * 64;    // wave N offset in tile

  // bijective XCD-aware block swizzle (nwg % 8 == 0 for all our launches)
  const int gx = gridDim.x;
  const int nwg = gx * gridDim.y;
  const int bid0 = blockIdx.y * gx + blockIdx.x;
  const int bid = (bid0 & 7) * (nwg >> 3) + (bid0 >> 3);
  const int bn0 = (bid % gx) * 256;
  const int bm0 = (bid / gx) * 256;

  const short* Wp = W;
  const float* bp = bias;
  int coff = 0;
  if (ZSEL && blockIdx.z) {
    Wp = Wz;
    bp = biasz;
    A += a_zoff;
    coff = c_zoff;
  }

  floatx16 acc[4][2];
#pragma unroll
  for (int mi = 0; mi < 4; ++mi)
#pragma unroll
    for (int nj = 0; nj < 2; ++nj)
#pragma unroll
      for (int q = 0; q < 16; ++q) acc[mi][nj][q] = 0.f;

  // staging: issue e covers rows e*8..e*8+7 (e = wid*4 + t, t=0..3 -> 256
  // rows across 8 waves); lane loads granule (lane&7)^r8 of row e*8+r8 ->
  // lands at LDS granule-slot (lane&7) of its row.
  const int r8 = lane >> 3;
  const int gsw = (lane & 7) ^ r8;
  const int aoff = r8 * lda + gsw * 8;  // per-lane element offset (VGPR)
  const int boff = r8 * K + gsw * 8;
  const short* Ab = A + (size_t)bm0 * lda;  // wave-uniform
  const short* Bb = Wp + (size_t)bn0 * K;   // wave-uniform
  const int e0 = __builtin_amdgcn_readfirstlane(wid * 4);

  short* As0 = lds;            // A slot0: 256x64
  short* As1 = lds + 16384;    // A slot1
  short* Bs0 = lds + 32768;    // B slot0
  short* Bs1 = lds + 49152;    // B slot1

#define STAGE_A(slotptr, t, tk0) \
  load16_lds(Ab + (size_t)(e0 + (t)) * 8 * lda + (tk0) + aoff, \
             (slotptr) + (e0 + (t)) * 512)
#define STAGE_B(slotptr, t, tk0) \
  load16_lds(Bb + (size_t)(e0 + (t)) * 8 * K + (tk0) + boff, \
             (slotptr) + (e0 + (t)) * 512)

  // phase p (one 16-wide k-step): stages | frag reads | barrier |
  // prio1 8x mfma_32x32x16 prio0 | [boundary vmcnt] | barrier.
#define PHASE(Asl, Bsl, p, STAGE_STMT, DOWAIT)                               \
  {                                                                          \
    STAGE_STMT;                                                              \
    const int ko = ((2 * (p) + lh) ^ swz7) * 8;                              \
    short8 av[4], bv[2];                                                     \
    _Pragma("unroll") for (int mi = 0; mi < 4; ++mi)                         \
        av[mi] = *(const short8*)&(Asl)[(wm + mi * 32 + l31) * 64 + ko];     \
    _Pragma("unroll") for (int nj = 0; nj < 2; ++nj)                         \
        bv[nj] = *(const short8*)&(Bsl)[(wn + nj * 32 + l31) * 64 + ko];     \
    asm volatile("" ::: "memory");                                           \
    __builtin_amdgcn_s_barrier();                                            \
    __builtin_amdgcn_s_setprio(1);                                           \
    _Pragma("unroll") for (int mi = 0; mi < 4; ++mi)                         \
        _Pragma("unroll") for (int nj = 0; nj < 2; ++nj)                     \
            acc[mi][nj] = __builtin_amdgcn_mfma_f32_32x32x16_bf16(           \
                av[mi], bv[nj], acc[mi][nj], 0, 0, 0);                       \
    __builtin_amdgcn_s_setprio(0);                                           \
    if (DOWAIT) asm volatile("s_waitcnt vmcnt(0)" ::: "memory");             \
    asm volatile("" ::: "memory");                                           \
    __builtin_amdgcn_s_barrier();                                            \
  }

  // prologue: stage tile0 -> slot0, drain, publish
#pragma unroll
  for (int t = 0; t < 4; ++t) {
    STAGE_A(As0, t, 0);
    STAGE_B(Bs0, t, 0);
  }
  asm volatile("s_waitcnt vmcnt(0)" ::: "memory");
  __builtin_amdgcn_s_barrier();

  const int nit = K >> 7;  // K/128 (two 64-wide tiles per iteration)
  for (int it = 0; it < nit; ++it) {
    const int kodd = it * 128 + 64;
    const int knext = it * 128 + 128;
    const bool more = (it + 1 < nit);
    // tile A: compute slot0 (k = it*128); stage odd tile -> slot1 early
    PHASE(As0, Bs0, 0,
          { STAGE_A(As1, 0, kodd); STAGE_B(Bs1, 0, kodd);
            STAGE_A(As1, 1, kodd); STAGE_B(Bs1, 1, kodd); }, 0)
    PHASE(As0, Bs0, 1,
          { STAGE_A(As1, 2, kodd); STAGE_B(Bs1, 2, kodd);
            STAGE_A(As1, 3, kodd); STAGE_B(Bs1, 3, kodd); }, 0)
    PHASE(As0, Bs0, 2, {}, 0)
    PHASE(As0, Bs0, 3, {}, 1)
    // tile B: compute slot1 (k = kodd); stage next even tile early
    PHASE(As1, Bs1, 0,
          { if (more) { STAGE_A(As0, 0, knext); STAGE_B(Bs0, 0, knext);
                        STAGE_A(As0, 1, knext); STAGE_B(Bs0, 1, knext); } }, 0)
    PHASE(As1, Bs1, 1,
          { if (more) { STAGE_A(As0, 2, knext); STAGE_B(Bs0, 2, knext);
                        STAGE_A(As0, 3, knext); STAGE_B(Bs0, 3, knext); } }, 0)
    PHASE(As1, Bs1, 2, {}, 0)
    PHASE(As1, Bs1, 3, {}, 1)
  }
#undef PHASE
#undef STAGE_A
#undef STAGE_B

  // epilogue (32x32 C/D): lane holds C[row][col] with
  // row = wm + mi*32 + (reg&3) + 8*(reg>>2) + 4*lh, col = wn + nj*32 + l31.
#pragma unroll
  for (int mi = 0; mi < 4; ++mi) {
#pragma unroll
    for (int nj = 0; nj < 2; ++nj) {
#pragma unroll
      for (int reg = 0; reg < 16; ++reg) {
        const int r = bm0 + wm + mi * 32 + (reg & 3) + 8 * (reg >> 2) + 4 * lh;
        const int n = bn0 + wn + nj * 32 + l31;
        float c = acc[mi][nj][reg];
        if (EPI == 0) {
          ((short*)Cout)[(size_t)r * ldc + n + coff] = f2b(c);
        } else if (EPI == 1) {
          ((short*)Cout)[(size_t)r * ldc + n + coff] =
              f2b(c + aux[(size_t)r * ld_aux + n]);
        } else if (EPI == 2) {
          ((short*)Cout)[(size_t)r * ldc + n + coff] =
              f2b(fast_tanh(c + bp[n]));
        } else {
          const float rv = b2f(res[(size_t)r * ldr + n + coff]);
          ((float*)Cout)[(size_t)r * ldc + n + coff] =
              fast_tanh(c + bp[n]) + rv;
        }
      }
    }
  }
}

// ---------------------------------------------------------------------------
// LayerNorm over (S,E) = 2048 elems per batch. One block per batch.
// ---------------------------------------------------------------------------
template <int INBF16>
__global__ __launch_bounds__(256) void ln_kernel(const void* __restrict__ xin,
                                                 const float* __restrict__ w,
                                                 const float* __restrict__ bb,
                                                 short* __restrict__ y) {
  const int b = blockIdx.x;
  const int tid = threadIdx.x;
  const size_t base = (size_t)b * 2048 + tid * 8;
  float xv[8];
  if (INBF16) {
    short8 s = *(const short8*)((const short*)xin + base);
#pragma unroll
    for (int j = 0; j < 8; ++j) xv[j] = b2f(s[j]);
  } else {
    const float4 a = *(const float4*)((const float*)xin + base);
    const float4 c = *(const float4*)((const float*)xin + base + 4);
    xv[0] = a.x; xv[1] = a.y; xv[2] = a.z; xv[3] = a.w;
    xv[4] = c.x; xv[5] = c.y; xv[6] = c.z; xv[7] = c.w;
  }
  float sum = 0.f, sq = 0.f;
#pragma unroll
  for (int j = 0; j < 8; ++j) {
    sum += xv[j];
    sq += xv[j] * xv[j];
  }
  __shared__ float rs[8];
  const int lane = tid & 63, wid = tid >> 6;
#pragma unroll
  for (int off = 32; off; off >>= 1) {
    sum += __shfl_down(sum, off);
    sq += __shfl_down(sq, off);
  }
  if (lane == 0) {
    rs[wid] = sum;
    rs[4 + wid] = sq;
  }
  __syncthreads();
  const float stot = rs[0] + rs[1] + rs[2] + rs[3];
  const float qtot = rs[4] + rs[5] + rs[6] + rs[7];
  const float mean = stot * (1.f / 2048.f);
  const float rstd = rsqrtf(qtot * (1.f / 2048.f) - mean * mean + 1e-5f);
  const int wi = tid * 8;
  short8 r;
#pragma unroll
  for (int j = 0; j < 8; ++j)
    r[j] = f2b((xv[j] - mean) * rstd * w[wi + j] + bb[wi + j]);
  *(short8*)(y + base) = r;
}

// ---------------------------------------------------------------------------
// Attention, S=2, on the fused QKV buffer (row stride 3072: q|k|v columns).
// ---------------------------------------------------------------------------
__global__ __launch_bounds__(256) void attn_kernel(short* qkv) {
  __shared__ short sm[2][6][1032];    // q0,q1,k0,k1,v0,v1
  __shared__ float sps[2][2][2][16];  // [half][s][t][h] scores
  __shared__ float spp[2][2][2][16];  // [half][s][t][h] probs
  const int tid = threadIdx.x;
  const int half = tid >> 7;
  const int t = tid & 127;
  const int b = blockIdx.x * 2 + half;
  const short* row0 = qkv + ((size_t)b * 2 + 0) * 3072;
  const short* row1 = qkv + ((size_t)b * 2 + 1) * 3072;
  const short* srcs[6] = {row0,        row1,        row0 + 1024,
                          row1 + 1024, row0 + 2048, row1 + 2048};
#pragma unroll
  for (int rr = 0; rr < 6; ++rr)
    *(short8*)&sm[half][rr][t * 8] = *(const short8*)(srcs[rr] + t * 8);
  __syncthreads();
  if (t < 64) {
    const int h = t & 15, comb = t >> 4;
    const int si = comb >> 1, ti = comb & 1;
    const short* qr = sm[half][si];
    const short* kr = sm[half][2 + ti];
    float a = 0.f;
#pragma unroll
    for (int d = 0; d < 64; ++d) a += b2f(qr[d * 16 + h]) * b2f(kr[d * 16 + h]);
    sps[half][si][ti][h] = a * 0.125f;  // / sqrt(NH=64)
  }
  __syncthreads();
  if (t < 32) {
    const int h = t & 15, si = t >> 4;
    const float s0 = sps[half][si][0][h], s1 = sps[half][si][1][h];
    const float m = fmaxf(s0, s1);
    const float e0 = __expf(s0 - m), e1 = __expf(s1 - m);
    const float inv = 1.f / (e0 + e1);
    spp[half][si][0][h] = e0 * inv;
    spp[half][si][1][h] = e1 * inv;
  }
  __syncthreads();
#pragma unroll
  for (int si = 0; si < 2; ++si) {
    short8 r;
#pragma unroll
    for (int j = 0; j < 8; ++j) {
      const int e = t * 8 + j;
      const int h = e & 15;
      const float c = spp[half][si][0][h] * b2f(sm[half][4][e]) +
                      spp[half][si][1][h] * b2f(sm[half][5][e]);
      r[j] = f2b(c);
    }
    *(short8*)(qkv + ((size_t)b * 2 + si) * 3072 + t * 8) = r;
  }
}

// ---------------------------------------------------------------------------
extern "C" void kernel_launch(void* const* d_in, const int* in_sizes, int n_in,
                              void* d_out, int out_size, void* d_ws,
                              size_t ws_size, hipStream_t stream) {
  (void)in_sizes; (void)n_in; (void)out_size; (void)ws_size;
  const float* input = (const float*)d_in[0];
  const float* Wq = (const float*)d_in[1];
  const float* Wk = (const float*)d_in[2];
  const float* Wv = (const float*)d_in[3];
  const float* Wo = (const float*)d_in[4];
  const float* ln1w = (const float*)d_in[5];
  const float* ln1b = (const float*)d_in[6];
  const float* ln2w = (const float*)d_in[7];
  const float* ln2b = (const float*)d_in[8];
  const float* f1w1 = (const float*)d_in[9];
  const float* f1b1 = (const float*)d_in[10];
  const float* f1w2 = (const float*)d_in[11];
  const float* f1b2 = (const float*)d_in[12];
  const float* f2w1 = (const float*)d_in[13];
  const float* f2b1 = (const float*)d_in[14];
  const float* f2w2 = (const float*)d_in[15];
  const float* f2b2 = (const float*)d_in[16];
  float* out = (float*)d_out;
  char* ws = (char*)d_ws;

  const size_t MB = 1024 * 1024;
  dim3 blk(256);
  dim3 gblk(512);
  const int GLDS = 131072;  // 128 KiB dynamic LDS for gemm256

  // allow 128 KiB dynamic LDS (idempotent, host-side, capture-safe)
  {
    auto set = [](const void* f) {
      (void)hipFuncSetAttribute(f, hipFuncAttributeMaxDynamicSharedMemorySize,
                                131072);
    };
    set((const void*)gemm256<0, 0>);
    set((const void*)gemm256<1, 0>);
    set((const void*)gemm256<2, 1>);
    set((const void*)gemm256<3, 1>);
  }

  // ws layout:
  //   phase 1: wqkv+wo [0,8) | xs->out1 [8,40) | qkv [40,136)   (136 MiB)
  //   phase 2: out1 [8,40) | fw [40,56) | hb [56,120)            (120 MiB)
  //   outs (LN2 output, 8192x2048 bf16 = 32 MiB) lives in d_out.
  short* wqkv = (short*)ws;
  short* wo = (short*)(ws + 6 * MB);
  short* xs = (short*)(ws + 8 * MB);
  short* out1 = xs;  // overwrites xs (dead after QKV GEMM)
  short* qkvb = (short*)(ws + 40 * MB);

  // ---- Phase 1 -----------------------------------------------------------
  {
    Src4 s{{Wq, Wk, Wv, Wo}};
    cvt4_kernel<<<2048, blk, 0, stream>>>(s, wqkv, 17);  // 4 x 1M elems
  }
  ln_kernel<0><<<8192, blk, 0, stream>>>(input, ln1w, ln1b, xs);
  {
    dim3 g(12, 64);  // 768 blocks, 1/CU -> 3 residency waves
    gemm256<0, 0><<<g, gblk, GLDS, stream>>>(xs, 1024, wqkv, 1024, qkvb, 3072,
                                             nullptr, 0, nullptr, nullptr, 0,
                                             nullptr, nullptr, 0, 0);
  }
  attn_kernel<<<4096, blk, 0, stream>>>(qkvb);
  {
    dim3 g(4, 64);  // 256 blocks = 1 residency wave
    // out1 = concat @ Wo^T + input  -> bf16 (overwrites xs)
    gemm256<1, 0><<<g, gblk, GLDS, stream>>>(qkvb, 3072, wo, 1024, out1, 1024,
                                             input, 1024, nullptr, nullptr, 0,
                                             nullptr, nullptr, 0, 0);
  }

  // ---- Phase 2 (unchunked) ----------------------------------------------
  short* fw1s0 = (short*)(ws + 40 * MB);
  short* fw1s1 = (short*)(ws + 44 * MB);
  short* fw2s0 = (short*)(ws + 48 * MB);
  short* fw2s1 = (short*)(ws + 52 * MB);
  short* hb = (short*)(ws + 56 * MB);  // 8192 x 4096 bf16 (64 MiB)
  short* outs = (short*)out;           // d_out reused as bf16 LN2 output
  {
    Src4 s{{f1w1, f2w1, f1w2, f2w2}};
    cvt4_kernel<<<4096, blk, 0, stream>>>(s, fw1s0, 18);  // 4 x 2M elems
  }
  ln_kernel<1><<<8192, blk, 0, stream>>>(out1, ln2w, ln2b, outs);
  {
    // h_s = tanh(outs_s @ w1_s^T + b1_s): M=8192, N=2048, K=1024, z=s
    dim3 g1(8, 32, 2);  // 512 blocks = 2 residency waves
    gemm256<2, 1><<<g1, gblk, GLDS, stream>>>(
        outs, 2048, fw1s0, 1024, hb, 4096, nullptr, 0, f1b1, nullptr, 0,
        fw1s1, f2b1, /*a_zoff=*/1024, /*c_zoff=*/2048);
    // out_s = tanh(h_s @ w2_s^T + b2_s) + out1_s  (fp32 -> d_out)
    dim3 g2(4, 32, 2);  // 256 blocks = 1 residency wave
    gemm256<3, 1><<<g2, gblk, GLDS, stream>>>(
        hb, 4096, fw2s0, 2048, out, 2048, nullptr, 0, f1b2, out1, 2048,
        fw2s1, f2b2, /*a_zoff=*/2048, /*c_zoff=*/1024);
  }
}

// Round 8
// 511.252 us; speedup vs baseline: 1.1098x; 1.0674x over previous
//
#include <hip/hip_runtime.h>
#include <hip/hip_bf16.h>
#include <stdint.h>

// ---------------------------------------------------------------------------
// InterFusion, fp32 I/O: LN1 -> QKV(fused N=3072) -> attn(S=2) ->
// O-proj(+resid -> out1 bf16 in ws) -> LN2 -> FFN1 -> FFN2(+resid -> fp32 out).
// GEMM: 256x256 tile, 8 waves (2Mx4N), mfma 16x16x32 (r4's proven shape).
// This round: T4 COUNTED VMCNT via a 4-slot BK=32 ring (4 x 16KiB x {A,B}
// = 128 KiB). 3 slots always in flight; boundary wait is vmcnt(8) (retire
// oldest slot, keep 8 loads flying) -- never vmcnt(0) in the main loop
// (m218: counted-vs-drain0 = +38%). Swizzle: slot-granule g of row r holds
// k-octet g ^ ((r>>1)&3) -- spreads reads over all 8 bank-groups, 2
// lanes each per 16-lane group (the r2-measured-0-conflict distribution;
// r7's (r&7) key at 128B stride degenerated and cost 9.4M conflicts).
// Barrier density, phase shape, setprio, XCD swizzle, epilogues = r4.
// ---------------------------------------------------------------------------

typedef __attribute__((ext_vector_type(8))) short short8;   // 8 bf16 = 4 VGPR
typedef __attribute__((ext_vector_type(4))) float floatx4;  // MFMA acc

__device__ __forceinline__ float b2f(short s) {
  union { unsigned u; float f; } v;
  v.u = ((unsigned)(unsigned short)s) << 16;
  return v.f;
}
__device__ __forceinline__ short f2b(float f) {
  union { float f; unsigned u; } v;
  v.f = f;
  unsigned r = v.u + 0x7FFFu + ((v.u >> 16) & 1u);  // RNE
  return (short)(r >> 16);
}
__device__ __forceinline__ float fast_tanh(float x) {
  float e = __expf(2.f * x);
  return 1.f - 2.f / (e + 1.f);
}
__device__ __forceinline__ void load16_lds(const void* g, void* l) {
  __builtin_amdgcn_global_load_lds(
      (__attribute__((address_space(1))) void*)(void*)g,
      (__attribute__((address_space(3))) void*)l, 16, 0, 0);
}

// ---------------------------------------------------------------------------
// 4-source fp32 -> bf16 conversion into one contiguous bf16 region.
// ---------------------------------------------------------------------------
struct Src4 { const float* p[4]; };

__global__ __launch_bounds__(256) void cvt4_kernel(Src4 s,
                                                   short* __restrict__ y,
                                                   int sh) {
  const int i = blockIdx.x * 256 + threadIdx.x;  // global 8-elem index
  const int seg = i >> sh;
  const int off = i & ((1 << sh) - 1);
  const float* x = s.p[seg];
  const float4 a = ((const float4*)x)[(size_t)off * 2];
  const float4 b = ((const float4*)x)[(size_t)off * 2 + 1];
  short8 r;
  r[0] = f2b(a.x); r[1] = f2b(a.y); r[2] = f2b(a.z); r[3] = f2b(a.w);
  r[4] = f2b(b.x); r[5] = f2b(b.y); r[6] = f2b(b.z); r[7] = f2b(b.w);
  ((short8*)y)[i] = r;
}

// ---------------------------------------------------------------------------
// GEMM: C[M,N] = A[M,K] @ W[N,K]^T (bf16 in, fp32 acc), 256x256 tile.
// grid = (N/256, M/256, ZSEL?2:1), block = 512 (8 waves, 2Mx4N of 128x64).
// LDS: A ring (4 x 256x32) | B ring (4 x 256x32), 128 KiB dynamic.
// Staging per 32-K slot: 4 loads/thread (2 A + 2 B); issue e = wid*2+t
// covers rows e*16..e*16+15; lane -> row e*16+(lane>>2), dest granule
// lane&3, source k-octet (lane&3)^((lane>>3)&3) -> slot-granule g of row
// r holds octet g^((r>>1)&3).
// Slot s compute = 2 phases (mh=0/1): {stages | 4(+4) frag reads | barrier
// | prio1 16x mfma_16x16x32 prio0 | [boundary wait] | barrier}.
// Pipeline: slots s+1..s+3 in flight; boundary vmcnt(8); tail 4/0.
// EPI 0: store bf16
// EPI 1: c + aux_f32[r][n], store bf16            (out1 = Oproj + input)
// EPI 2: tanh(c + bias[n]), store bf16            (FFN hidden)
// EPI 3: tanh(c + bias[n]) + b2f(res_bf16), store fp32   (final output)
// ZSEL: blockIdx.z==1 -> Wz/biasz, A += a_zoff, C/res += c_zoff.
// ---------------------------------------------------------------------------
template <int EPI, int ZSEL>
__global__ __launch_bounds__(512, 2) void gemm256(
    const short* A, int lda, const short* W, int K, void* Cout, int ldc,
    const float* aux, int ld_aux, const float* bias, const short* res, int ldr,
    const short* Wz, const float* biasz, int a_zoff, int c_zoff) {
  extern __shared__ short lds[];  // 65536 shorts = 128 KiB
  const int tid = threadIdx.x;
  const int lane = tid & 63;
  const int wid = tid >> 6;
  const int l15 = lane & 15;
  const int l4 = lane >> 4;         // k-octet selector (0..3)
  const int wm = (wid >> 2) * 128;  // wave M offset in tile
  const int wn = (wid & 3) * 64;    // wave N offset in tile

  // bijective XCD-aware block swizzle (nwg % 8 == 0 for all our launches)
  const int gx = gridDim.x;
  const int nwg = gx * gridDim.y;
  const int bid0 = blockIdx.y * gx + blockIdx.x;
  const int bid = (bid0 & 7) * (nwg >> 3) + (bid0 >> 3);
  const int bn0 = (bid % gx) * 256;
  const int bm0 = (bid / gx) * 256;

  const short* Wp = W;
  const float* bp = bias;
  int coff = 0;
  if (ZSEL && blockIdx.z) {
    Wp = Wz;
    bp = biasz;
    A += a_zoff;
    coff = c_zoff;
  }

  floatx4 zero = {0.f, 0.f, 0.f, 0.f};
  floatx4 acc[8][4];
#pragma unroll
  for (int i = 0; i < 8; ++i)
#pragma unroll
    for (int j = 0; j < 4; ++j) acc[i][j] = zero;

  // staging addressing (per-lane constants)
  const int r16 = lane >> 2;                       // row within 16-group
  const int srcg = (lane & 3) ^ ((lane >> 3) & 3); // source k-octet
  const int aoff = r16 * lda + srcg * 8;           // element offset (VGPR)
  const int boff = r16 * K + srcg * 8;
  const short* Ab = A + (size_t)bm0 * lda;   // wave-uniform
  const short* Bb = Wp + (size_t)bn0 * K;    // wave-uniform
  const int e0 = __builtin_amdgcn_readfirstlane(wid * 2);
  // read-side: slot-granule = l4 ^ ((l15>>1)&3), constant for all slots
  const int ko = ((l4 ^ ((l15 >> 1) & 3)) * 8);

  // ring: A slot p at lds + p*8192, B slot p at lds + 32768 + p*8192
#define STAGE_A32(p, t, kb) \
  load16_lds(Ab + (size_t)(e0 + (t)) * 16 * lda + (kb) + aoff, \
             lds + (p) * 8192 + (e0 + (t)) * 512)
#define STAGE_B32(p, t, kb) \
  load16_lds(Bb + (size_t)(e0 + (t)) * 16 * K + (kb) + boff, \
             lds + 32768 + (p) * 8192 + (e0 + (t)) * 512)

  // one 32-K slot: 2 phases. DOSTAGE stages slot (np) at k-base (kb).
  // WAITSTMT runs before the final barrier (counted vmcnt).
#define SLOT32(sp, np, kb, DOSTAGE, WAITSTMT)                                \
  {                                                                          \
    const short* Ap = lds + (sp) * 8192;                                     \
    const short* Bp = lds + 32768 + (sp) * 8192;                             \
    short8 av[4], bv[4];                                                     \
    if (DOSTAGE) { STAGE_A32(np, 0, kb); STAGE_A32(np, 1, kb); }             \
    _Pragma("unroll") for (int j = 0; j < 4; ++j)                            \
        bv[j] = *(const short8*)&Bp[(wn + j * 16 + l15) * 32 + ko];          \
    _Pragma("unroll") for (int i = 0; i < 4; ++i)                            \
        av[i] = *(const short8*)&Ap[(wm + i * 16 + l15) * 32 + ko];          \
    asm volatile("" ::: "memory");                                           \
    __builtin_amdgcn_s_barrier();                                            \
    __builtin_amdgcn_s_setprio(1);                                           \
    _Pragma("unroll") for (int i = 0; i < 4; ++i)                            \
        _Pragma("unroll") for (int j = 0; j < 4; ++j)                        \
            acc[i][j] = __builtin_amdgcn_mfma_f32_16x16x32_bf16(             \
                av[i], bv[j], acc[i][j], 0, 0, 0);                           \
    __builtin_amdgcn_s_setprio(0);                                           \
    asm volatile("" ::: "memory");                                           \
    __builtin_amdgcn_s_barrier();                                            \
    if (DOSTAGE) { STAGE_B32(np, 0, kb); STAGE_B32(np, 1, kb); }             \
    _Pragma("unroll") for (int i = 0; i < 4; ++i)                            \
        av[i] = *(const short8*)&Ap[(wm + 64 + i * 16 + l15) * 32 + ko];     \
    asm volatile("" ::: "memory");                                           \
    __builtin_amdgcn_s_barrier();                                            \
    __builtin_amdgcn_s_setprio(1);                                           \
    _Pragma("unroll") for (int i = 0; i < 4; ++i)                            \
        _Pragma("unroll") for (int j = 0; j < 4; ++j)                        \
            acc[4 + i][j] = __builtin_amdgcn_mfma_f32_16x16x32_bf16(         \
                av[i], bv[j], acc[4 + i][j], 0, 0, 0);                       \
    __builtin_amdgcn_s_setprio(0);                                           \
    WAITSTMT;                                                                \
    asm volatile("" ::: "memory");                                           \
    __builtin_amdgcn_s_barrier();                                            \
  }

  // prologue: stage slots 0,1,2 (12 loads); retire slot0 (vmcnt(8)).
#pragma unroll
  for (int t = 0; t < 2; ++t) { STAGE_A32(0, t, 0);  STAGE_B32(0, t, 0); }
#pragma unroll
  for (int t = 0; t < 2; ++t) { STAGE_A32(1, t, 32); STAGE_B32(1, t, 32); }
#pragma unroll
  for (int t = 0; t < 2; ++t) { STAGE_A32(2, t, 64); STAGE_B32(2, t, 64); }
  asm volatile("s_waitcnt vmcnt(8)" ::: "memory");
  __builtin_amdgcn_s_barrier();

  const int nk = K >> 5;  // 32-K slots (>= 32 for all our K)
  for (int s = 0; s + 3 < nk; ++s) {
    SLOT32(s & 3, (s + 3) & 3, (s + 3) * 32, 1,
           asm volatile("s_waitcnt vmcnt(8)" ::: "memory"))
  }
  SLOT32((nk - 3) & 3, 0, 0, 0, asm volatile("s_waitcnt vmcnt(4)" ::: "memory"))
  SLOT32((nk - 2) & 3, 0, 0, 0, asm volatile("s_waitcnt vmcnt(0)" ::: "memory"))
  SLOT32((nk - 1) & 3, 0, 0, 0, (void)0)
#undef SLOT32
#undef STAGE_A32
#undef STAGE_B32

  // epilogue: lane holds C[mb + i*16 + p][nb + j*16], p = 0..3, i = 0..7
  const int mb = bm0 + wm + l4 * 4;
  const int nb = bn0 + wn + l15;
#pragma unroll
  for (int i = 0; i < 8; ++i) {
#pragma unroll
    for (int p = 0; p < 4; ++p) {
      const int r = mb + i * 16 + p;
#pragma unroll
      for (int j = 0; j < 4; ++j) {
        const int n = nb + j * 16;
        float c = acc[i][j][p];
        if (EPI == 0) {
          ((short*)Cout)[(size_t)r * ldc + n + coff] = f2b(c);
        } else if (EPI == 1) {
          ((short*)Cout)[(size_t)r * ldc + n + coff] =
              f2b(c + aux[(size_t)r * ld_aux + n]);
        } else if (EPI == 2) {
          ((short*)Cout)[(size_t)r * ldc + n + coff] =
              f2b(fast_tanh(c + bp[n]));
        } else {
          const float rv = b2f(res[(size_t)r * ldr + n + coff]);
          ((float*)Cout)[(size_t)r * ldc + n + coff] =
              fast_tanh(c + bp[n]) + rv;
        }
      }
    }
  }
}

// ---------------------------------------------------------------------------
// LayerNorm over (S,E) = 2048 elems per batch. One block per batch.
// ---------------------------------------------------------------------------
template <int INBF16>
__global__ __launch_bounds__(256) void ln_kernel(const void* __restrict__ xin,
                                                 const float* __restrict__ w,
                                                 const float* __restrict__ bb,
                                                 short* __restrict__ y) {
  const int b = blockIdx.x;
  const int tid = threadIdx.x;
  const size_t base = (size_t)b * 2048 + tid * 8;
  float xv[8];
  if (INBF16) {
    short8 s = *(const short8*)((const short*)xin + base);
#pragma unroll
    for (int j = 0; j < 8; ++j) xv[j] = b2f(s[j]);
  } else {
    const float4 a = *(const float4*)((const float*)xin + base);
    const float4 c = *(const float4*)((const float*)xin + base + 4);
    xv[0] = a.x; xv[1] = a.y; xv[2] = a.z; xv[3] = a.w;
    xv[4] = c.x; xv[5] = c.y; xv[6] = c.z; xv[7] = c.w;
  }
  float sum = 0.f, sq = 0.f;
#pragma unroll
  for (int j = 0; j < 8; ++j) {
    sum += xv[j];
    sq += xv[j] * xv[j];
  }
  __shared__ float rs[8];
  const int lane = tid & 63, wid = tid >> 6;
#pragma unroll
  for (int off = 32; off; off >>= 1) {
    sum += __shfl_down(sum, off);
    sq += __shfl_down(sq, off);
  }
  if (lane == 0) {
    rs[wid] = sum;
    rs[4 + wid] = sq;
  }
  __syncthreads();
  const float stot = rs[0] + rs[1] + rs[2] + rs[3];
  const float qtot = rs[4] + rs[5] + rs[6] + rs[7];
  const float mean = stot * (1.f / 2048.f);
  const float rstd = rsqrtf(qtot * (1.f / 2048.f) - mean * mean + 1e-5f);
  const int wi = tid * 8;
  short8 r;
#pragma unroll
  for (int j = 0; j < 8; ++j)
    r[j] = f2b((xv[j] - mean) * rstd * w[wi + j] + bb[wi + j]);
  *(short8*)(y + base) = r;
}

// ---------------------------------------------------------------------------
// Attention, S=2, on the fused QKV buffer (row stride 3072: q|k|v columns).
// ---------------------------------------------------------------------------
__global__ __launch_bounds__(256) void attn_kernel(short* qkv) {
  __shared__ short sm[2][6][1032];    // q0,q1,k0,k1,v0,v1
  __shared__ float sps[2][2][2][16];  // [half][s][t][h] scores
  __shared__ float spp[2][2][2][16];  // [half][s][t][h] probs
  const int tid = threadIdx.x;
  const int half = tid >> 7;
  const int t = tid & 127;
  const int b = blockIdx.x * 2 + half;
  const short* row0 = qkv + ((size_t)b * 2 + 0) * 3072;
  const short* row1 = qkv + ((size_t)b * 2 + 1) * 3072;
  const short* srcs[6] = {row0,        row1,        row0 + 1024,
                          row1 + 1024, row0 + 2048, row1 + 2048};
#pragma unroll
  for (int rr = 0; rr < 6; ++rr)
    *(short8*)&sm[half][rr][t * 8] = *(const short8*)(srcs[rr] + t * 8);
  __syncthreads();
  if (t < 64) {
    const int h = t & 15, comb = t >> 4;
    const int si = comb >> 1, ti = comb & 1;
    const short* qr = sm[half][si];
    const short* kr = sm[half][2 + ti];
    float a = 0.f;
#pragma unroll
    for (int d = 0; d < 64; ++d) a += b2f(qr[d * 16 + h]) * b2f(kr[d * 16 + h]);
    sps[half][si][ti][h] = a * 0.125f;  // / sqrt(NH=64)
  }
  __syncthreads();
  if (t < 32) {
    const int h = t & 15, si = t >> 4;
    const float s0 = sps[half][si][0][h], s1 = sps[half][si][1][h];
    const float m = fmaxf(s0, s1);
    const float e0 = __expf(s0 - m), e1 = __expf(s1 - m);
    const float inv = 1.f / (e0 + e1);
    spp[half][si][0][h] = e0 * inv;
    spp[half][si][1][h] = e1 * inv;
  }
  __syncthreads();
#pragma unroll
  for (int si = 0; si < 2; ++si) {
    short8 r;
#pragma unroll
    for (int j = 0; j < 8; ++j) {
      const int e = t * 8 + j;
      const int h = e & 15;
      const float c = spp[half][si][0][h] * b2f(sm[half][4][e]) +
                      spp[half][si][1][h] * b2f(sm[half][5][e]);
      r[j] = f2b(c);
    }
    *(short8*)(qkv + ((size_t)b * 2 + si) * 3072 + t * 8) = r;
  }
}

// ---------------------------------------------------------------------------
extern "C" void kernel_launch(void* const* d_in, const int* in_sizes, int n_in,
                              void* d_out, int out_size, void* d_ws,
                              size_t ws_size, hipStream_t stream) {
  (void)in_sizes; (void)n_in; (void)out_size; (void)ws_size;
  const float* input = (const float*)d_in[0];
  const float* Wq = (const float*)d_in[1];
  const float* Wk = (const float*)d_in[2];
  const float* Wv = (const float*)d_in[3];
  const float* Wo = (const float*)d_in[4];
  const float* ln1w = (const float*)d_in[5];
  const float* ln1b = (const float*)d_in[6];
  const float* ln2w = (const float*)d_in[7];
  const float* ln2b = (const float*)d_in[8];
  const float* f1w1 = (const float*)d_in[9];
  const float* f1b1 = (const float*)d_in[10];
  const float* f1w2 = (const float*)d_in[11];
  const float* f1b2 = (const float*)d_in[12];
  const float* f2w1 = (const float*)d_in[13];
  const float* f2b1 = (const float*)d_in[14];
  const float* f2w2 = (const float*)d_in[15];
  const float* f2b2 = (const float*)d_in[16];
  float* out = (float*)d_out;
  char* ws = (char*)d_ws;

  const size_t MB = 1024 * 1024;
  dim3 blk(256);
  dim3 gblk(512);
  const int GLDS = 131072;  // 128 KiB dynamic LDS for gemm256

  // allow 128 KiB dynamic LDS (idempotent, host-side, capture-safe)
  {
    auto set = [](const void* f) {
      (void)hipFuncSetAttribute(f, hipFuncAttributeMaxDynamicSharedMemorySize,
                                131072);
    };
    set((const void*)gemm256<0, 0>);
    set((const void*)gemm256<1, 0>);
    set((const void*)gemm256<2, 1>);
    set((const void*)gemm256<3, 1>);
  }

  // ws layout:
  //   phase 1: wqkv+wo [0,8) | xs->out1 [8,40) | qkv [40,136)   (136 MiB)
  //   phase 2: out1 [8,40) | fw [40,56) | hb [56,120)            (120 MiB)
  //   outs (LN2 output, 8192x2048 bf16 = 32 MiB) lives in d_out.
  short* wqkv = (short*)ws;
  short* wo = (short*)(ws + 6 * MB);
  short* xs = (short*)(ws + 8 * MB);
  short* out1 = xs;  // overwrites xs (dead after QKV GEMM)
  short* qkvb = (short*)(ws + 40 * MB);

  // ---- Phase 1 -----------------------------------------------------------
  {
    Src4 s{{Wq, Wk, Wv, Wo}};
    cvt4_kernel<<<2048, blk, 0, stream>>>(s, wqkv, 17);  // 4 x 1M elems
  }
  ln_kernel<0><<<8192, blk, 0, stream>>>(input, ln1w, ln1b, xs);
  {
    dim3 g(12, 64);  // 768 blocks, 1/CU -> 3 residency waves
    gemm256<0, 0><<<g, gblk, GLDS, stream>>>(xs, 1024, wqkv, 1024, qkvb, 3072,
                                             nullptr, 0, nullptr, nullptr, 0,
                                             nullptr, nullptr, 0, 0);
  }
  attn_kernel<<<4096, blk, 0, stream>>>(qkvb);
  {
    dim3 g(4, 64);  // 256 blocks = 1 residency wave
    // out1 = concat @ Wo^T + input  -> bf16 (overwrites xs)
    gemm256<1, 0><<<g, gblk, GLDS, stream>>>(qkvb, 3072, wo, 1024, out1, 1024,
                                             input, 1024, nullptr, nullptr, 0,
                                             nullptr, nullptr, 0, 0);
  }

  // ---- Phase 2 (unchunked) ----------------------------------------------
  short* fw1s0 = (short*)(ws + 40 * MB);
  short* fw1s1 = (short*)(ws + 44 * MB);
  short* fw2s0 = (short*)(ws + 48 * MB);
  short* fw2s1 = (short*)(ws + 52 * MB);
  short* hb = (short*)(ws + 56 * MB);  // 8192 x 4096 bf16 (64 MiB)
  short* outs = (short*)out;           // d_out reused as bf16 LN2 output
  {
    Src4 s{{f1w1, f2w1, f1w2, f2w2}};
    cvt4_kernel<<<4096, blk, 0, stream>>>(s, fw1s0, 18);  // 4 x 2M elems
  }
  ln_kernel<1><<<8192, blk, 0, stream>>>(out1, ln2w, ln2b, outs);
  {
    // h_s = tanh(outs_s @ w1_s^T + b1_s): M=8192, N=2048, K=1024, z=s
    dim3 g1(8, 32, 2);  // 512 blocks = 2 residency waves
    gemm256<2, 1><<<g1, gblk, GLDS, stream>>>(
        outs, 2048, fw1s0, 1024, hb, 4096, nullptr, 0, f1b1, nullptr, 0,
        fw1s1, f2b1, /*a_zoff=*/1024, /*c_zoff=*/2048);
    // out_s = tanh(h_s @ w2_s^T + b2_s) + out1_s  (fp32 -> d_out)
    dim3 g2(4, 32, 2);  // 256 blocks = 1 residency wave
    gemm256<3, 1><<<g2, gblk, GLDS, stream>>>(
        hb, 4096, fw2s0, 2048, out, 2048, nullptr, 0, f1b2, out1, 2048,
        fw2s1, f2b2, /*a_zoff=*/2048, /*c_zoff=*/1024);
  }
}